// Round 1
// baseline (2648.569 us; speedup 1.0000x reference)
//
#include <hip/hip_runtime.h>
#include <hip/hip_bf16.h>

#define N_NODES_C 100000
#define N_EDGES_C 1600000
#define N_BUCK ((N_NODES_C + 255) / 256)   // 391
#define BCAP 4608                          // per-bucket capacity, mean 4096 + 8 sigma
#define PART_NB 160
#define PART_CHUNK ((N_EDGES_C + PART_NB - 1) / PART_NB)  // 10000

// push-gather geometry
#define PUSH_NODES 64
#define ACC_STRIDE 132                      // 128 + 4 pad (bank spread)
#define AGG_BLOCKS ((N_NODES_C + PUSH_NODES - 1) / PUSH_NODES)  // 1563
#define CH_SHIFT 12                         // src chunk = src>>12 (25 chunks, 1 MB bf16 each)

typedef __attribute__((ext_vector_type(8))) short          short8;   // 8 bf16
typedef __attribute__((ext_vector_type(4))) float          f32x4;
typedef __attribute__((ext_vector_type(4))) unsigned int   u32x4;
typedef __attribute__((ext_vector_type(4))) unsigned short u16x4;

// ---------------------------------------------------------------------------
__device__ inline float load1v(const void* p, size_t i, int bf) {
    return bf ? __bfloat162float(((const __hip_bfloat16*)p)[i])
              : ((const float*)p)[i];
}
__device__ inline unsigned short f2bf(float f) {
    __hip_bfloat16 h = __float2bfloat16(f);
    return *reinterpret_cast<unsigned short*>(&h);
}
__device__ inline float bf_lo(unsigned u) { return __uint_as_float(u << 16); }
__device__ inline float bf_hi(unsigned u) { return __uint_as_float(u & 0xffff0000u); }
__device__ inline void acc8(float* a, u32x4 r) {
    a[0] += bf_lo(r.x); a[1] += bf_hi(r.x);
    a[2] += bf_lo(r.y); a[3] += bf_hi(r.y);
    a[4] += bf_lo(r.z); a[5] += bf_hi(r.z);
    a[6] += bf_lo(r.w); a[7] += bf_hi(r.w);
}
// LDS push: feat f of node row ap lives at ap[(f&7)*16 + (f>>3)] (16x8 transpose
// so a 16-lane x 8-feat ds_add sweep hits 16 consecutive banks per instruction).
__device__ inline void lds_acc(float* ap, int sub, u32x4 r) {
    atomicAdd(ap + 0 * 16 + sub, bf_lo(r.x));
    atomicAdd(ap + 1 * 16 + sub, bf_hi(r.x));
    atomicAdd(ap + 2 * 16 + sub, bf_lo(r.y));
    atomicAdd(ap + 3 * 16 + sub, bf_hi(r.y));
    atomicAdd(ap + 4 * 16 + sub, bf_lo(r.z));
    atomicAdd(ap + 5 * 16 + sub, bf_hi(r.z));
    atomicAdd(ap + 6 * 16 + sub, bf_lo(r.w));
    atomicAdd(ap + 7 * 16 + sub, bf_hi(r.w));
}

// ---------------------------------------------------------------------------
// Dtype probe (gflag=1 iff float tensors are bf16) + bucket cursor init.
__global__ void detect_init(const void* __restrict__ feats, int* __restrict__ gflag,
                            int* __restrict__ bcur) {
    const unsigned short* u = (const unsigned short*)feats;
    int bad = 0;
    for (int i = threadIdx.x; i < 2048; i += 64) {
        unsigned e = (u[i] >> 7) & 0xFF;
        if (e >= 0xC0) bad++;
    }
#pragma unroll
    for (int off = 32; off > 0; off >>= 1) bad += __shfl_down(bad, off, 64);
    if (threadIdx.x == 0) *gflag = (bad == 0) ? 1 : 0;
    for (int b = threadIdx.x; b < N_BUCK; b += 64) bcur[b] = b * BCAP;
}

// ---------------------------------------------------------------------------
// Privatized two-pass partition into FIXED-CAP bucket slots.
__global__ __launch_bounds__(256) void partition2(
        const int* __restrict__ src, const int* __restrict__ dst,
        int* __restrict__ bcur, unsigned* __restrict__ pairs) {
    __shared__ int cnt[N_BUCK];
    __shared__ int lbase[N_BUCK];
    int tid = threadIdx.x;
    int e0 = blockIdx.x * PART_CHUNK;
    int e1 = min(e0 + PART_CHUNK, N_EDGES_C);
    for (int i = tid; i < N_BUCK; i += 256) cnt[i] = 0;
    __syncthreads();
    for (int e = e0 + tid; e < e1; e += 256)
        atomicAdd(&cnt[dst[e] >> 8], 1);
    __syncthreads();
    for (int i = tid; i < N_BUCK; i += 256) {
        int c = cnt[i];
        lbase[i] = c ? atomicAdd(&bcur[i], c) : 0;
        cnt[i] = 0;                       // reuse as local cursor
    }
    __syncthreads();
    for (int e = e0 + tid; e < e1; e += 256) {
        int s = src[e], d = dst[e];
        int bk = d >> 8;
        int pos = lbase[bk] + atomicAdd(&cnt[bk], 1);
        pairs[pos] = ((unsigned)(d & 255) << 17) | (unsigned)s;
    }
}

// Compact csr offsets from bucket fill levels (LDS-staged)
__global__ void mkboff_kernel(const int* __restrict__ bcur, int* __restrict__ boff) {
    __shared__ int c[N_BUCK];
    int tid = threadIdx.x;
    for (int i = tid; i < N_BUCK; i += 64) c[i] = bcur[i] - i * BCAP;
    __syncthreads();
    if (tid == 0) {
        int run = 0;
        for (int b = 0; b < N_BUCK; ++b) { int t = c[b]; c[b] = run; run += t; }
        boff[N_BUCK] = run;
    }
    __syncthreads();
    for (int i = tid; i < N_BUCK; i += 64) boff[i] = c[i];
}

// One block per bucket: per-node count + LDS scan -> row_start/deg, then emit
// csr (compact layout at boff) from the padded pairs window at b*BCAP.
// NEW: second counting sort by (sub2, wave, src-chunk) into cedges + woff,
// feeding the chunk-phased push_gather.
__global__ __launch_bounds__(256) void bucket_fill(
        const unsigned* __restrict__ pairs, const int* __restrict__ boff,
        int* __restrict__ csr, int* __restrict__ row_start, int* __restrict__ deg,
        unsigned* __restrict__ cedges, int* __restrict__ woff) {
    __shared__ int cnt[256], sd[256], lcur[256];
    __shared__ int kcnt[1024];
    int b = blockIdx.x, tid = threadIdx.x;
    int pbase = b * BCAP;
    int base = boff[b], count = boff[b + 1] - base;
    cnt[tid] = 0;
    __syncthreads();
    for (int i = tid; i < count; i += 256)
        atomicAdd(&cnt[pairs[pbase + i] >> 17], 1);
    __syncthreads();
    sd[tid] = cnt[tid];
    __syncthreads();
    for (int st = 1; st < 256; st <<= 1) {
        int t = (tid >= st) ? sd[tid - st] : 0;
        __syncthreads();
        sd[tid] += t;
        __syncthreads();
    }
    int excl = sd[tid] - cnt[tid];
    int node = b * 256 + tid;
    if (node < N_NODES_C) { row_start[node] = base + excl; deg[node] = cnt[tid]; }
    lcur[tid] = excl;
    __syncthreads();
    for (int i = tid; i < count; i += 256) {
        unsigned p = pairs[pbase + i];
        int pos = base + atomicAdd(&lcur[p >> 17], 1);
        csr[pos] = (int)(p & 0x1FFFFu);
    }

    // ---- chunk sort: key = sub2(2b) | wave(3b) | chunk(5b) ----
    for (int i = tid; i < 1024; i += 256) kcnt[i] = 0;
    __syncthreads();
    for (int i = tid; i < count; i += 256) {
        unsigned p = pairs[pbase + i];
        int key = (((p >> 23) & 3) << 8) | (((p >> 20) & 7) << 5)
                | ((p & 0x1FFFFu) >> CH_SHIFT);
        atomicAdd(&kcnt[key], 1);
    }
    __syncthreads();
    int s0 = kcnt[tid * 4 + 0], s1 = kcnt[tid * 4 + 1];
    int s2 = kcnt[tid * 4 + 2], s3 = kcnt[tid * 4 + 3];
    int tsum = s0 + s1 + s2 + s3;
    sd[tid] = tsum;
    __syncthreads();
    for (int st = 1; st < 256; st <<= 1) {
        int t = (tid >= st) ? sd[tid - st] : 0;
        __syncthreads();
        sd[tid] += t;
        __syncthreads();
    }
    int ex = sd[tid] - tsum;
    kcnt[tid * 4 + 0] = ex;
    kcnt[tid * 4 + 1] = ex + s0;
    kcnt[tid * 4 + 2] = ex + s0 + s1;
    kcnt[tid * 4 + 3] = ex + s0 + s1 + s2;
    __syncthreads();
    if (tid < 32) {
        int sub2 = tid >> 3, wv = tid & 7;
        woff[(b * 4 + sub2) * 8 + wv] = base + kcnt[(sub2 << 8) | (wv << 5)];
    }
    __syncthreads();
    for (int i = tid; i < count; i += 256) {
        unsigned p = pairs[pbase + i];
        int key = (((p >> 23) & 3) << 8) | (((p >> 20) & 7) << 5)
                | ((p & 0x1FFFFu) >> CH_SHIFT);
        int pos = base + atomicAdd(&kcnt[key], 1);
        cedges[pos] = p;
    }
}

// ---------------------------------------------------------------------------
// Weight prep. Wt rows 0..127: L0 (K=256); 128..255: L1 (K=256);
// L2 compact at Wt+65536: 80 rows x K=128 (cols 0..39 = Ws2, 40..79 = Wn2).
__global__ void prep_weights(const void* Ws0, const void* bs0, const void* Wn0, const void* bn0,
                             const void* Ws1, const void* bs1, const void* Wn1, const void* bn1,
                             const void* Ws2, const void* bs2, const void* Wn2, const void* bn2,
                             unsigned short* __restrict__ Wt, float* __restrict__ bcat,
                             const int* __restrict__ gflag) {
    int gb = *gflag;
    int n = blockIdx.x;        // 0..335
    int k = threadIdx.x;       // 0..255
    if (n < 128) {
        float v = (k < 128) ? load1v(Ws0, (size_t)k * 128 + n, gb)
                            : load1v(Wn0, (size_t)(k - 128) * 128 + n, gb);
        Wt[(size_t)n * 256 + k] = f2bf(v);
        if (k == 0) bcat[n] = load1v(bs0, n, gb) + load1v(bn0, n, gb);
    } else if (n < 256) {
        int c = n - 128;
        float v = (k < 128) ? load1v(Ws1, (size_t)k * 128 + c, gb)
                            : load1v(Wn1, (size_t)(k - 128) * 128 + c, gb);
        Wt[(size_t)n * 256 + k] = f2bf(v);
        if (k == 0) bcat[n] = load1v(bs1, c, gb) + load1v(bn1, c, gb);
    } else {
        int c = n - 256;       // 0..79
        if (k < 128) {
            float v = (c < 40) ? load1v(Ws2, (size_t)k * 40 + c, gb)
                               : load1v(Wn2, (size_t)k * 40 + (c - 40), gb);
            Wt[65536 + (size_t)c * 128 + k] = f2bf(v);
        }
        if (k == 0) bcat[n] = (c < 40) ? load1v(bs2, c, gb) + load1v(bn2, c, gb) : 0.0f;
    }
}

// ---------------------------------------------------------------------------
// Chunk-phased LDS-push aggregation. One block per 64 dst nodes; f32 acc in
// LDS (transposed layout); per-wave disjoint dst ownership via the sort key;
// edges consumed in src-chunk order so concurrently-resident blocks sweep the
// same 1 MB source chunk and L2 captures duplicate row reads.
__global__ __launch_bounds__(512) void push_gather(
        const void* __restrict__ hsrc, int src_stride,
        int src_mode, int copy_self,
        const unsigned* __restrict__ cedges, const int* __restrict__ woff,
        const int* __restrict__ deg,
        unsigned short* __restrict__ X,
        const int* __restrict__ gflag) {
    __shared__ float acc[PUSH_NODES * ACC_STRIDE];   // 33,792 B -> 4 blocks/CU
    int tid = threadIdx.x;
    int b = blockIdx.x;
    for (int i = tid; i < PUSH_NODES * ACC_STRIDE; i += 512) acc[i] = 0.0f;
    __syncthreads();

    int wave = tid >> 6, lane = tid & 63;
    int bf = (src_mode == 2) ? *gflag : src_mode;
    int e0 = woff[b * 8 + wave], e1 = woff[b * 8 + wave + 1];

    if (bf) {
        int g = lane >> 4, sub = lane & 15;
        const unsigned short* hb = (const unsigned short*)hsrc;
        for (int base = e0; base < e1; base += 64) {
            int n64 = min(e1 - base, 64);
            int ce_r = (int)cedges[base + ((lane < n64) ? lane : 0)];
            int nq = n64 >> 2, rem = n64 & 3;
            int i = 0;
            for (; i + 4 <= nq; i += 4) {
                int c0 = __shfl(ce_r, (i + 0) * 4 + g, 64);
                int c1 = __shfl(ce_r, (i + 1) * 4 + g, 64);
                int c2 = __shfl(ce_r, (i + 2) * 4 + g, 64);
                int c3 = __shfl(ce_r, (i + 3) * 4 + g, 64);
                u32x4 r0 = *(const u32x4*)(hb + (size_t)(c0 & 0x1FFFF) * src_stride + sub * 8);
                u32x4 r1 = *(const u32x4*)(hb + (size_t)(c1 & 0x1FFFF) * src_stride + sub * 8);
                u32x4 r2 = *(const u32x4*)(hb + (size_t)(c2 & 0x1FFFF) * src_stride + sub * 8);
                u32x4 r3 = *(const u32x4*)(hb + (size_t)(c3 & 0x1FFFF) * src_stride + sub * 8);
                lds_acc(acc + ((c0 >> 17) & 63) * ACC_STRIDE, sub, r0);
                lds_acc(acc + ((c1 >> 17) & 63) * ACC_STRIDE, sub, r1);
                lds_acc(acc + ((c2 >> 17) & 63) * ACC_STRIDE, sub, r2);
                lds_acc(acc + ((c3 >> 17) & 63) * ACC_STRIDE, sub, r3);
            }
            for (; i < nq; ++i) {
                int c0 = __shfl(ce_r, i * 4 + g, 64);
                u32x4 r0 = *(const u32x4*)(hb + (size_t)(c0 & 0x1FFFF) * src_stride + sub * 8);
                lds_acc(acc + ((c0 >> 17) & 63) * ACC_STRIDE, sub, r0);
            }
            if (rem) {
                int c0 = __shfl(ce_r, nq * 4 + g, 64);
                if (g < rem) {
                    u32x4 r0 = *(const u32x4*)(hb + (size_t)(c0 & 0x1FFFF) * src_stride + sub * 8);
                    lds_acc(acc + ((c0 >> 17) & 63) * ACC_STRIDE, sub, r0);
                }
            }
        }
    } else {
        int g = lane >> 4, sub = lane & 15;
        const float* hf = (const float*)hsrc;
        for (int base = e0; base < e1; base += 64) {
            int n64 = min(e1 - base, 64);
            int ce_r = (int)cedges[base + ((lane < n64) ? lane : 0)];
            int nq = n64 >> 2, rem = n64 & 3;
            for (int i = 0; i < nq; ++i) {
                int ce = __shfl(ce_r, i * 4 + g, 64);
                const float* rp = hf + (size_t)(ce & 0x1FFFF) * src_stride + sub * 4;
                f32x4 ra = *(const f32x4*)rp;
                f32x4 rb = *(const f32x4*)(rp + 64);
                float* ap = acc + ((ce >> 17) & 63) * ACC_STRIDE;
#pragma unroll
                for (int k = 0; k < 4; ++k) {
                    int fA = 4 * sub + k;
                    atomicAdd(ap + (fA & 7) * 16 + (fA >> 3), ra[k]);
                    int fB = 64 + 4 * sub + k;
                    atomicAdd(ap + (fB & 7) * 16 + (fB >> 3), rb[k]);
                }
            }
            if (rem) {
                int ce = __shfl(ce_r, nq * 4 + g, 64);
                if (g < rem) {
                    const float* rp = hf + (size_t)(ce & 0x1FFFF) * src_stride + sub * 4;
                    f32x4 ra = *(const f32x4*)rp;
                    f32x4 rb = *(const f32x4*)(rp + 64);
                    float* ap = acc + ((ce >> 17) & 63) * ACC_STRIDE;
#pragma unroll
                    for (int k = 0; k < 4; ++k) {
                        int fA = 4 * sub + k;
                        atomicAdd(ap + (fA & 7) * 16 + (fA >> 3), ra[k]);
                        int fB = 64 + 4 * sub + k;
                        atomicAdd(ap + (fB & 7) * 16 + (fB >> 3), rb[k]);
                    }
                }
            }
        }
    }
    __syncthreads();

    // finalize: each wave writes its 8 nodes (mean + optional self copy)
    int fg = lane >> 4, fsub = lane & 15;
    int gn_base = b * PUSH_NODES;
#pragma unroll
    for (int r = 0; r < 2; ++r) {
        int n = wave * 8 + r * 4 + fg;
        int gn = gn_base + n;
        if (gn < N_NODES_C) {
            int d = deg[gn];
            float inv = (d > 0) ? 1.0f / (float)d : 0.0f;
            float v[8];
#pragma unroll
            for (int j = 0; j < 8; ++j)
                v[j] = acc[n * ACC_STRIDE + j * 16 + fsub] * inv;
            u32x4 o;
            o.x = (unsigned)f2bf(v[0]) | ((unsigned)f2bf(v[1]) << 16);
            o.y = (unsigned)f2bf(v[2]) | ((unsigned)f2bf(v[3]) << 16);
            o.z = (unsigned)f2bf(v[4]) | ((unsigned)f2bf(v[5]) << 16);
            o.w = (unsigned)f2bf(v[6]) | ((unsigned)f2bf(v[7]) << 16);
            *(u32x4*)(X + (size_t)gn * 256 + 128 + fsub * 8) = o;
            if (copy_self) {
                if (bf) {
                    u32x4 raw = *(const u32x4*)((const unsigned short*)hsrc
                                  + (size_t)gn * src_stride + fsub * 8);
                    *(u32x4*)(X + (size_t)gn * 256 + fsub * 8) = raw;
                } else {
                    const float* hf = (const float*)hsrc;
                    f32x4 ra = *(const f32x4*)(hf + (size_t)gn * src_stride + fsub * 4);
                    f32x4 rb = *(const f32x4*)(hf + (size_t)gn * src_stride + 64 + fsub * 4);
                    u16x4 oa = { f2bf(ra.x), f2bf(ra.y), f2bf(ra.z), f2bf(ra.w) };
                    u16x4 ob = { f2bf(rb.x), f2bf(rb.y), f2bf(rb.z), f2bf(rb.w) };
                    *(u16x4*)(X + (size_t)gn * 256 + fsub * 4) = oa;
                    *(u16x4*)(X + (size_t)gn * 256 + 64 + fsub * 4) = ob;
                }
            }
        }
    }
}

// ---------------------------------------------------------------------------
// MFMA GEMM. DUAL=false: out[node][c] bf16, stride out_stride (layers 0/1).
// DUAL=true: cols 0..39 -> Zbuf (stride 40), cols 40..79 -> Ybuf (stride 40).
template <int NCT, int KT, int CHK, bool ACTNORM, bool DUAL>
__global__ __launch_bounds__(256) void mfma_gemm(
        const unsigned short* __restrict__ X, int astride,
        const u32x4* __restrict__ Wg,           // [NCT*16][CHK] 16B chunks
        const float* __restrict__ bias,         // [NCT*16]
        unsigned short* __restrict__ out, int out_stride,
        unsigned short* __restrict__ Ybuf, unsigned short* __restrict__ Zbuf,
        int n_nodes) {
    __shared__ u32x4 ldsW[NCT * 16 * CHK];
    int tid = threadIdx.x;
    for (int c = tid; c < NCT * 16 * CHK; c += 256) {
        int nrow = c / CHK, ch = c % CHK;
        ldsW[nrow * CHK + (ch ^ (nrow & 7))] = Wg[c];
    }
    __syncthreads();

    int wave = tid >> 6, lane = tid & 63;
    int quad = lane >> 4, sub = lane & 15;
    int mynode = blockIdx.x * 64 + wave * 16 + sub;
    int arow = (mynode < n_nodes) ? mynode : (n_nodes - 1);
    const unsigned short* ap = X + (size_t)arow * astride + quad * 8;

    f32x4 acc[NCT];
#pragma unroll
    for (int ct = 0; ct < NCT; ++ct) acc[ct] = (f32x4){0,0,0,0};

    short8 av = *(const short8*)ap;
#pragma unroll
    for (int kt = 0; kt < KT; ++kt) {
        short8 av_next = av;
        if (kt < KT - 1) av_next = *(const short8*)(ap + (kt + 1) * 32);
        int chunk = kt * 4 + quad;
#pragma unroll
        for (int ct = 0; ct < NCT; ++ct) {
            int ncol = ct * 16 + sub;
            union { u32x4 u; short8 s; } cv;
            cv.u = ldsW[ncol * CHK + (chunk ^ (ncol & 7))];
            acc[ct] = __builtin_amdgcn_mfma_f32_16x16x32_bf16(cv.s, av, acc[ct], 0, 0, 0);
        }
        av = av_next;
    }

    float ss = 0.0f;
#pragma unroll
    for (int ct = 0; ct < NCT; ++ct) {
        f32x4 b4 = *(const f32x4*)(bias + ct * 16 + quad * 4);
#pragma unroll
        for (int r = 0; r < 4; ++r) {
            float v = acc[ct][r] + b4[r];
            if (ACTNORM) { v = fmaxf(v, 0.0f); ss += v * v; }
            acc[ct][r] = v;
        }
    }
    float scale = 1.0f;
    if (ACTNORM) {
        ss += __shfl_xor(ss, 16, 64);
        ss += __shfl_xor(ss, 32, 64);
        scale = 1.0f / fmaxf(sqrtf(ss), 1e-12f);
    }
    if (mynode < n_nodes) {
#pragma unroll
        for (int ct = 0; ct < NCT; ++ct) {
            int c0 = ct * 16 + quad * 4;
            u16x4 o = { f2bf(acc[ct][0] * scale), f2bf(acc[ct][1] * scale),
                        f2bf(acc[ct][2] * scale), f2bf(acc[ct][3] * scale) };
            if (DUAL) {
                if (c0 < 40) *(u16x4*)(Zbuf + (size_t)mynode * 40 + c0) = o;
                else         *(u16x4*)(Ybuf + (size_t)mynode * 40 + (c0 - 40)) = o;
            } else {
                *(u16x4*)(out + (size_t)mynode * out_stride + c0) = o;
            }
        }
    }
}

// ---------------------------------------------------------------------------
// Layer-2 finish: out[n] = mean_{nb}(Y2[nb]) + Z2[n]. One wave per node,
// 8 lanes per 80B Y2 row (stride 40; lanes 5..7 read in-region garbage that is
// discarded by the sub<5 write guard and never crosses the shfl_xor groups).
__global__ void combine_kernel(const unsigned short* __restrict__ Y2,
                               const unsigned short* __restrict__ Z2,
                               const int* __restrict__ csr,
                               const int* __restrict__ row_start,
                               const int* __restrict__ deg,
                               void* __restrict__ out,
                               const int* __restrict__ gflag) {
    int node = blockIdx.x * 4 + (threadIdx.x >> 6);
    if (node >= N_NODES_C) return;
    int lane = threadIdx.x & 63;
    int g = lane >> 3, sub = lane & 7;
    int start = row_start[node], d = deg[node];
    const int* cp = csr + start;
    float a[8] = {0,0,0,0,0,0,0,0};
    int rd = (sub < 5) ? sub : 4;          // keep OOB-safe within allocated rows
    int nfull = d >> 3, rem = d & 7;
    int i = 0;
    for (; i + 2 <= nfull; i += 2) {
        int nb0 = cp[i * 8 + g];
        int nb1 = cp[i * 8 + 8 + g];
        u32x4 r0 = *(const u32x4*)(Y2 + (size_t)nb0 * 40 + rd * 8);
        u32x4 r1 = *(const u32x4*)(Y2 + (size_t)nb1 * 40 + rd * 8);
        acc8(a, r0); acc8(a, r1);
    }
    if (i < nfull) {
        int nb = cp[i * 8 + g];
        u32x4 r = *(const u32x4*)(Y2 + (size_t)nb * 40 + rd * 8);
        acc8(a, r);
    }
    if (g < rem) {
        int nb = cp[nfull * 8 + g];
        u32x4 r = *(const u32x4*)(Y2 + (size_t)nb * 40 + rd * 8);
        acc8(a, r);
    }
#pragma unroll
    for (int j = 0; j < 8; ++j) {
        a[j] += __shfl_xor(a[j], 8, 64);
        a[j] += __shfl_xor(a[j], 16, 64);
        a[j] += __shfl_xor(a[j], 32, 64);
    }
    if (g == 0 && sub < 5) {
        float inv = (d > 0) ? 1.0f / (float)d : 0.0f;
        u32x4 z = *(const u32x4*)(Z2 + (size_t)node * 40 + sub * 8);
        float v[8];
        v[0] = a[0] * inv + bf_lo(z.x); v[1] = a[1] * inv + bf_hi(z.x);
        v[2] = a[2] * inv + bf_lo(z.y); v[3] = a[3] * inv + bf_hi(z.y);
        v[4] = a[4] * inv + bf_lo(z.z); v[5] = a[5] * inv + bf_hi(z.z);
        v[6] = a[6] * inv + bf_lo(z.w); v[7] = a[7] * inv + bf_hi(z.w);
        if (*gflag) {
            u32x4 o;
            o.x = (unsigned)f2bf(v[0]) | ((unsigned)f2bf(v[1]) << 16);
            o.y = (unsigned)f2bf(v[2]) | ((unsigned)f2bf(v[3]) << 16);
            o.z = (unsigned)f2bf(v[4]) | ((unsigned)f2bf(v[5]) << 16);
            o.w = (unsigned)f2bf(v[6]) | ((unsigned)f2bf(v[7]) << 16);
            *(u32x4*)((unsigned short*)out + (size_t)node * 40 + sub * 8) = o;
        } else {
            float* op = (float*)out + (size_t)node * 40 + sub * 8;
            f32x4 o0 = { v[0], v[1], v[2], v[3] };
            f32x4 o1 = { v[4], v[5], v[6], v[7] };
            *(f32x4*)op = o0;
            *(f32x4*)(op + 4) = o1;
        }
    }
}

// ---------------------------------------------------------------------------
extern "C" void kernel_launch(void* const* d_in, const int* in_sizes, int n_in,
                              void* d_out, int out_size, void* d_ws, size_t ws_size,
                              hipStream_t stream) {
    const void* feats = d_in[0];
    const int*  src   = (const int*)d_in[1];
    const int*  dst   = (const int*)d_in[2];

    char* ws = (char*)d_ws;
    unsigned short* X0   = (unsigned short*)ws;                        // 51,200,000
    unsigned short* X1   = (unsigned short*)(ws + 51200000);           // 51,200,000
    unsigned short* Wt   = (unsigned short*)(ws + 102400000);          //   ~283,000
    float*          bcat = (float*)(ws + 102912000);                   //     1,344
    unsigned short* Y2   = (unsigned short*)(ws + 102916096);          //  8,000,000 (stride 40)
    unsigned short* Z2   = (unsigned short*)(ws + 115716096);          //  8,000,000 (stride 40)
    unsigned*       pairs= (unsigned*)(ws + 102916096);                // alias Y2 (pre-GEMM only), 7.2 MB
    unsigned*       cedges=(unsigned*)(ws + 115716096);                // alias Z2 (pre-GEMM only), 6.4 MB
    int*  csr       = (int*)(ws + 128516096);                          //  6,400,000
    int*  row_start = (int*)(ws + 134916096);                          //    400,000
    int*  deg       = (int*)(ws + 135316096);                          //    400,000
    int*  boff      = (int*)(ws + 135718144);                          // (N_BUCK+1)*4
    int*  bcur      = (int*)(ws + 135720192);                          // N_BUCK*4
    int*  gflag     = (int*)(ws + 135722240);
    int*  woff      = (int*)(ws + 135722496);                          // 12512*4 = 50 KB

    // ---- dtype probe + bucket cursor init (no memsets needed) ----
    detect_init<<<1, 64, 0, stream>>>(feats, gflag, bcur);

    // ---- bucketed CSR build + chunk-sorted edge list ----
    partition2<<<PART_NB, 256, 0, stream>>>(src, dst, bcur, pairs);
    mkboff_kernel<<<1, 64, 0, stream>>>(bcur, boff);
    bucket_fill<<<N_BUCK, 256, 0, stream>>>(pairs, boff, csr, row_start, deg, cedges, woff);

    // ---- weights ----
    prep_weights<<<336, 256, 0, stream>>>(
        d_in[3], d_in[4], d_in[5], d_in[6],
        d_in[7], d_in[8], d_in[9], d_in[10],
        d_in[11], d_in[12], d_in[13], d_in[14], Wt, bcat, gflag);

    const int gblk = (N_NODES_C + 3) / 4;
    const int mblk = (N_NODES_C + 63) / 64;

    // layer 0: feats -> X0 = [self | mean] -> X1[:,0:128]
    push_gather<<<AGG_BLOCKS, 512, 0, stream>>>(feats, 128, 2, 1, cedges, woff, deg, X0, gflag);
    mfma_gemm<8, 8, 32, true, false><<<mblk, 256, 0, stream>>>(
        X0, 256, (const u32x4*)Wt, bcat, X1, 256, nullptr, nullptr, N_NODES_C);

    // layer 1: X1 -> X0[:,0:128]
    push_gather<<<AGG_BLOCKS, 512, 0, stream>>>(X1, 256, 1, 0, cedges, woff, deg, X1, gflag);
    mfma_gemm<8, 8, 32, true, false><<<mblk, 256, 0, stream>>>(
        X1, 256, (const u32x4*)(Wt + 128 * 256), bcat + 128, X0, 256, nullptr, nullptr, N_NODES_C);

    // layer 2 (transform-then-aggregate): h2 -> Y2 = h2@Wn2, Z2 = h2@Ws2 + b
    mfma_gemm<5, 4, 16, false, true><<<mblk, 256, 0, stream>>>(
        X0, 256, (const u32x4*)(Wt + 65536), bcat + 256, nullptr, 0, Y2, Z2, N_NODES_C);

    // out = mean(Y2[nbrs]) + Z2
    combine_kernel<<<gblk, 256, 0, stream>>>(Y2, Z2, csr, row_start, deg, d_out, gflag);
}

// Round 2
// 463.438 us; speedup vs baseline: 5.7150x; 5.7150x over previous
//
#include <hip/hip_runtime.h>
#include <hip/hip_bf16.h>

#define N_NODES_C 100000
#define N_EDGES_C 1600000
#define N_BUCK ((N_NODES_C + 255) / 256)   // 391
#define BCAP 4608                          // per-bucket capacity, mean 4092 + 8 sigma
#define PART_NB 160
#define PART_CHUNK ((N_EDGES_C + PART_NB - 1) / PART_NB)  // 10000

typedef __attribute__((ext_vector_type(8))) short          short8;   // 8 bf16
typedef __attribute__((ext_vector_type(4))) float          f32x4;
typedef __attribute__((ext_vector_type(4))) unsigned int   u32x4;
typedef __attribute__((ext_vector_type(4))) unsigned short u16x4;

// ---------------------------------------------------------------------------
__device__ inline float load1v(const void* p, size_t i, int bf) {
    return bf ? __bfloat162float(((const __hip_bfloat16*)p)[i])
              : ((const float*)p)[i];
}
__device__ inline unsigned short f2bf(float f) {
    __hip_bfloat16 h = __float2bfloat16(f);
    return *reinterpret_cast<unsigned short*>(&h);
}
__device__ inline float bf_lo(unsigned u) { return __uint_as_float(u << 16); }
__device__ inline float bf_hi(unsigned u) { return __uint_as_float(u & 0xffff0000u); }
__device__ inline void acc8(float* a, u32x4 r) {
    a[0] += bf_lo(r.x); a[1] += bf_hi(r.x);
    a[2] += bf_lo(r.y); a[3] += bf_hi(r.y);
    a[4] += bf_lo(r.z); a[5] += bf_hi(r.z);
    a[6] += bf_lo(r.w); a[7] += bf_hi(r.w);
}

// ---------------------------------------------------------------------------
// Dtype probe (gflag=1 iff float tensors are bf16) + bucket cursor init.
__global__ void detect_init(const void* __restrict__ feats, int* __restrict__ gflag,
                            int* __restrict__ bcur) {
    const unsigned short* u = (const unsigned short*)feats;
    int bad = 0;
    for (int i = threadIdx.x; i < 2048; i += 64) {
        unsigned e = (u[i] >> 7) & 0xFF;
        if (e >= 0xC0) bad++;
    }
#pragma unroll
    for (int off = 32; off > 0; off >>= 1) bad += __shfl_down(bad, off, 64);
    if (threadIdx.x == 0) *gflag = (bad == 0) ? 1 : 0;
    for (int b = threadIdx.x; b < N_BUCK; b += 64) bcur[b] = b * BCAP;
}

// ---------------------------------------------------------------------------
// Privatized two-pass partition into FIXED-CAP bucket slots.
__global__ __launch_bounds__(256) void partition2(
        const int* __restrict__ src, const int* __restrict__ dst,
        int* __restrict__ bcur, unsigned* __restrict__ pairs) {
    __shared__ int cnt[N_BUCK];
    __shared__ int lbase[N_BUCK];
    int tid = threadIdx.x;
    int e0 = blockIdx.x * PART_CHUNK;
    int e1 = min(e0 + PART_CHUNK, N_EDGES_C);
    for (int i = tid; i < N_BUCK; i += 256) cnt[i] = 0;
    __syncthreads();
    for (int e = e0 + tid; e < e1; e += 256)
        atomicAdd(&cnt[dst[e] >> 8], 1);
    __syncthreads();
    for (int i = tid; i < N_BUCK; i += 256) {
        int c = cnt[i];
        lbase[i] = c ? atomicAdd(&bcur[i], c) : 0;
        cnt[i] = 0;                       // reuse as local cursor
    }
    __syncthreads();
    for (int e = e0 + tid; e < e1; e += 256) {
        int s = src[e], d = dst[e];
        int bk = d >> 8;
        int pos = lbase[bk] + atomicAdd(&cnt[bk], 1);
        pairs[pos] = ((unsigned)(d & 255) << 17) | (unsigned)s;
    }
}

// Compact csr offsets from bucket fill levels (LDS-staged)
__global__ void mkboff_kernel(const int* __restrict__ bcur, int* __restrict__ boff) {
    __shared__ int c[N_BUCK];
    int tid = threadIdx.x;
    for (int i = tid; i < N_BUCK; i += 64) c[i] = bcur[i] - i * BCAP;
    __syncthreads();
    if (tid == 0) {
        int run = 0;
        for (int b = 0; b < N_BUCK; ++b) { int t = c[b]; c[b] = run; run += t; }
        boff[N_BUCK] = run;
    }
    __syncthreads();
    for (int i = tid; i < N_BUCK; i += 64) boff[i] = c[i];
}

// One block per bucket: per-node count + LDS scan -> row_start/deg, then emit
// csr (compact layout at boff) from the padded pairs window at b*BCAP.
__global__ __launch_bounds__(256) void bucket_fill(
        const unsigned* __restrict__ pairs, const int* __restrict__ boff,
        int* __restrict__ csr, int* __restrict__ row_start, int* __restrict__ deg) {
    __shared__ int cnt[256], sd[256], lcur[256];
    int b = blockIdx.x, tid = threadIdx.x;
    int pbase = b * BCAP;
    int base = boff[b], count = boff[b + 1] - base;
    cnt[tid] = 0;
    __syncthreads();
    for (int i = tid; i < count; i += 256)
        atomicAdd(&cnt[pairs[pbase + i] >> 17], 1);
    __syncthreads();
    sd[tid] = cnt[tid];
    __syncthreads();
    for (int st = 1; st < 256; st <<= 1) {
        int t = (tid >= st) ? sd[tid - st] : 0;
        __syncthreads();
        sd[tid] += t;
        __syncthreads();
    }
    int excl = sd[tid] - cnt[tid];
    int node = b * 256 + tid;
    if (node < N_NODES_C) { row_start[node] = base + excl; deg[node] = cnt[tid]; }
    lcur[tid] = excl;
    __syncthreads();
    for (int i = tid; i < count; i += 256) {
        unsigned p = pairs[pbase + i];
        int pos = base + atomicAdd(&lcur[p >> 17], 1);
        csr[pos] = (int)(p & 0x1FFFFu);
    }
}

// ---------------------------------------------------------------------------
// Weight prep. Wt rows 0..127: L0 (K=256); 128..255: L1 (K=256);
// L2 compact at Wt+65536: 80 rows x K=128 (cols 0..39 = Ws2, 40..79 = Wn2).
__global__ void prep_weights(const void* Ws0, const void* bs0, const void* Wn0, const void* bn0,
                             const void* Ws1, const void* bs1, const void* Wn1, const void* bn1,
                             const void* Ws2, const void* bs2, const void* Wn2, const void* bn2,
                             unsigned short* __restrict__ Wt, float* __restrict__ bcat,
                             const int* __restrict__ gflag) {
    int gb = *gflag;
    int n = blockIdx.x;        // 0..335
    int k = threadIdx.x;       // 0..255
    if (n < 128) {
        float v = (k < 128) ? load1v(Ws0, (size_t)k * 128 + n, gb)
                            : load1v(Wn0, (size_t)(k - 128) * 128 + n, gb);
        Wt[(size_t)n * 256 + k] = f2bf(v);
        if (k == 0) bcat[n] = load1v(bs0, n, gb) + load1v(bn0, n, gb);
    } else if (n < 256) {
        int c = n - 128;
        float v = (k < 128) ? load1v(Ws1, (size_t)k * 128 + c, gb)
                            : load1v(Wn1, (size_t)(k - 128) * 128 + c, gb);
        Wt[(size_t)n * 256 + k] = f2bf(v);
        if (k == 0) bcat[n] = load1v(bs1, c, gb) + load1v(bn1, c, gb);
    } else {
        int c = n - 256;       // 0..79
        if (k < 128) {
            float v = (c < 40) ? load1v(Ws2, (size_t)k * 40 + c, gb)
                               : load1v(Wn2, (size_t)k * 40 + (c - 40), gb);
            Wt[65536 + (size_t)c * 128 + k] = f2bf(v);
        }
        if (k == 0) bcat[n] = (c < 40) ? load1v(bs2, c, gb) + load1v(bn2, c, gb) : 0.0f;
    }
}

// ---------------------------------------------------------------------------
// Gather-mean into X[:,128:256] (bf16). v4: one node per 16-lane GROUP
// (4 nodes/wave). Each group reads full 256B rows (16 lanes x 16B); per-lane
// private accumulation (no cross-lane reduce); waves live 4x longer with up
// to 8 row-loads in flight -> sustained MLP instead of degree-bounded MLP.
__global__ __launch_bounds__(256) void gather_kernel(
        const void* __restrict__ hsrc, int src_stride,
        int src_mode, int copy_self,
        const int* __restrict__ csr,
        const int* __restrict__ row_start,
        const int* __restrict__ deg,
        unsigned short* __restrict__ X,
        const int* __restrict__ gflag) {
    int wave = threadIdx.x >> 6, lane = threadIdx.x & 63;
    int g = lane >> 4, sub = lane & 15;
    int srcLane = lane & 48;                       // g*16
    int node = blockIdx.x * 16 + wave * 4 + g;
    bool valid = node < N_NODES_C;
    int vnode = valid ? node : (N_NODES_C - 1);
    int start = row_start[vnode];
    int d = valid ? deg[vnode] : 0;
    const int* cp = csr + start;
    float inv = (d > 0) ? 1.0f / (float)d : 0.0f;
    int bf = (src_mode == 2) ? *gflag : src_mode;

    if (bf) {
        const unsigned short* hb = (const unsigned short*)hsrc;
        float a[8] = {0, 0, 0, 0, 0, 0, 0, 0};
        for (int base = 0; base < d; base += 16) {
            int n16 = min(d - base, 16);
            int idxr = cp[base + ((sub < n16) ? sub : 0)];
            int i = 0;
            for (; i + 8 <= n16; i += 8) {
                int nb0 = __shfl(idxr, srcLane + i + 0, 64);
                int nb1 = __shfl(idxr, srcLane + i + 1, 64);
                int nb2 = __shfl(idxr, srcLane + i + 2, 64);
                int nb3 = __shfl(idxr, srcLane + i + 3, 64);
                int nb4 = __shfl(idxr, srcLane + i + 4, 64);
                int nb5 = __shfl(idxr, srcLane + i + 5, 64);
                int nb6 = __shfl(idxr, srcLane + i + 6, 64);
                int nb7 = __shfl(idxr, srcLane + i + 7, 64);
                u32x4 r0 = *(const u32x4*)(hb + (size_t)nb0 * src_stride + sub * 8);
                u32x4 r1 = *(const u32x4*)(hb + (size_t)nb1 * src_stride + sub * 8);
                u32x4 r2 = *(const u32x4*)(hb + (size_t)nb2 * src_stride + sub * 8);
                u32x4 r3 = *(const u32x4*)(hb + (size_t)nb3 * src_stride + sub * 8);
                u32x4 r4 = *(const u32x4*)(hb + (size_t)nb4 * src_stride + sub * 8);
                u32x4 r5 = *(const u32x4*)(hb + (size_t)nb5 * src_stride + sub * 8);
                u32x4 r6 = *(const u32x4*)(hb + (size_t)nb6 * src_stride + sub * 8);
                u32x4 r7 = *(const u32x4*)(hb + (size_t)nb7 * src_stride + sub * 8);
                acc8(a, r0); acc8(a, r1); acc8(a, r2); acc8(a, r3);
                acc8(a, r4); acc8(a, r5); acc8(a, r6); acc8(a, r7);
            }
            for (; i + 4 <= n16; i += 4) {
                int nb0 = __shfl(idxr, srcLane + i + 0, 64);
                int nb1 = __shfl(idxr, srcLane + i + 1, 64);
                int nb2 = __shfl(idxr, srcLane + i + 2, 64);
                int nb3 = __shfl(idxr, srcLane + i + 3, 64);
                u32x4 r0 = *(const u32x4*)(hb + (size_t)nb0 * src_stride + sub * 8);
                u32x4 r1 = *(const u32x4*)(hb + (size_t)nb1 * src_stride + sub * 8);
                u32x4 r2 = *(const u32x4*)(hb + (size_t)nb2 * src_stride + sub * 8);
                u32x4 r3 = *(const u32x4*)(hb + (size_t)nb3 * src_stride + sub * 8);
                acc8(a, r0); acc8(a, r1); acc8(a, r2); acc8(a, r3);
            }
            for (; i < n16; ++i) {
                int nb = __shfl(idxr, srcLane + i, 64);
                u32x4 r = *(const u32x4*)(hb + (size_t)nb * src_stride + sub * 8);
                acc8(a, r);
            }
        }
        if (valid) {
            u32x4 o;
            o.x = (unsigned)f2bf(a[0] * inv) | ((unsigned)f2bf(a[1] * inv) << 16);
            o.y = (unsigned)f2bf(a[2] * inv) | ((unsigned)f2bf(a[3] * inv) << 16);
            o.z = (unsigned)f2bf(a[4] * inv) | ((unsigned)f2bf(a[5] * inv) << 16);
            o.w = (unsigned)f2bf(a[6] * inv) | ((unsigned)f2bf(a[7] * inv) << 16);
            *(u32x4*)(X + (size_t)node * 256 + 128 + sub * 8) = o;
            if (copy_self) {
                u32x4 raw = *(const u32x4*)(hb + (size_t)node * src_stride + sub * 8);
                *(u32x4*)(X + (size_t)node * 256 + sub * 8) = raw;
            }
        }
    } else {
        const float* hf = (const float*)hsrc;
        float a[8] = {0, 0, 0, 0, 0, 0, 0, 0};
        for (int base = 0; base < d; base += 16) {
            int n16 = min(d - base, 16);
            int idxr = cp[base + ((sub < n16) ? sub : 0)];
            int i = 0;
            for (; i + 4 <= n16; i += 4) {
                int nb0 = __shfl(idxr, srcLane + i + 0, 64);
                int nb1 = __shfl(idxr, srcLane + i + 1, 64);
                int nb2 = __shfl(idxr, srcLane + i + 2, 64);
                int nb3 = __shfl(idxr, srcLane + i + 3, 64);
                const float* p0 = hf + (size_t)nb0 * src_stride + sub * 4;
                const float* p1 = hf + (size_t)nb1 * src_stride + sub * 4;
                const float* p2 = hf + (size_t)nb2 * src_stride + sub * 4;
                const float* p3 = hf + (size_t)nb3 * src_stride + sub * 4;
                f32x4 a0 = *(const f32x4*)p0, b0 = *(const f32x4*)(p0 + 64);
                f32x4 a1 = *(const f32x4*)p1, b1 = *(const f32x4*)(p1 + 64);
                f32x4 a2 = *(const f32x4*)p2, b2 = *(const f32x4*)(p2 + 64);
                f32x4 a3 = *(const f32x4*)p3, b3 = *(const f32x4*)(p3 + 64);
#pragma unroll
                for (int k = 0; k < 4; ++k) {
                    a[k] += a0[k] + a1[k] + a2[k] + a3[k];
                    a[4 + k] += b0[k] + b1[k] + b2[k] + b3[k];
                }
            }
            for (; i < n16; ++i) {
                int nb = __shfl(idxr, srcLane + i, 64);
                const float* p0 = hf + (size_t)nb * src_stride + sub * 4;
                f32x4 a0 = *(const f32x4*)p0, b0 = *(const f32x4*)(p0 + 64);
#pragma unroll
                for (int k = 0; k < 4; ++k) { a[k] += a0[k]; a[4 + k] += b0[k]; }
            }
        }
        if (valid) {
            u16x4 oa = { f2bf(a[0] * inv), f2bf(a[1] * inv),
                         f2bf(a[2] * inv), f2bf(a[3] * inv) };
            u16x4 ob = { f2bf(a[4] * inv), f2bf(a[5] * inv),
                         f2bf(a[6] * inv), f2bf(a[7] * inv) };
            *(u16x4*)(X + (size_t)node * 256 + 128 + sub * 4) = oa;
            *(u16x4*)(X + (size_t)node * 256 + 128 + 64 + sub * 4) = ob;
            if (copy_self) {
                const float* sp = hf + (size_t)node * src_stride + sub * 4;
                f32x4 ra = *(const f32x4*)sp;
                f32x4 rb = *(const f32x4*)(sp + 64);
                u16x4 sa = { f2bf(ra.x), f2bf(ra.y), f2bf(ra.z), f2bf(ra.w) };
                u16x4 sb = { f2bf(rb.x), f2bf(rb.y), f2bf(rb.z), f2bf(rb.w) };
                *(u16x4*)(X + (size_t)node * 256 + sub * 4) = sa;
                *(u16x4*)(X + (size_t)node * 256 + 64 + sub * 4) = sb;
            }
        }
    }
}

// ---------------------------------------------------------------------------
// MFMA GEMM. DUAL=false: out[node][c] bf16, stride out_stride (layers 0/1).
// DUAL=true: cols 0..39 -> Zbuf (stride 40), cols 40..79 -> Ybuf (stride 40).
template <int NCT, int KT, int CHK, bool ACTNORM, bool DUAL>
__global__ __launch_bounds__(256) void mfma_gemm(
        const unsigned short* __restrict__ X, int astride,
        const u32x4* __restrict__ Wg,           // [NCT*16][CHK] 16B chunks
        const float* __restrict__ bias,         // [NCT*16]
        unsigned short* __restrict__ out, int out_stride,
        unsigned short* __restrict__ Ybuf, unsigned short* __restrict__ Zbuf,
        int n_nodes) {
    __shared__ u32x4 ldsW[NCT * 16 * CHK];
    int tid = threadIdx.x;
    for (int c = tid; c < NCT * 16 * CHK; c += 256) {
        int nrow = c / CHK, ch = c % CHK;
        ldsW[nrow * CHK + (ch ^ (nrow & 7))] = Wg[c];
    }
    __syncthreads();

    int wave = tid >> 6, lane = tid & 63;
    int quad = lane >> 4, sub = lane & 15;
    int mynode = blockIdx.x * 64 + wave * 16 + sub;
    int arow = (mynode < n_nodes) ? mynode : (n_nodes - 1);
    const unsigned short* ap = X + (size_t)arow * astride + quad * 8;

    f32x4 acc[NCT];
#pragma unroll
    for (int ct = 0; ct < NCT; ++ct) acc[ct] = (f32x4){0,0,0,0};

    short8 av = *(const short8*)ap;
#pragma unroll
    for (int kt = 0; kt < KT; ++kt) {
        short8 av_next = av;
        if (kt < KT - 1) av_next = *(const short8*)(ap + (kt + 1) * 32);
        int chunk = kt * 4 + quad;
#pragma unroll
        for (int ct = 0; ct < NCT; ++ct) {
            int ncol = ct * 16 + sub;
            union { u32x4 u; short8 s; } cv;
            cv.u = ldsW[ncol * CHK + (chunk ^ (ncol & 7))];
            acc[ct] = __builtin_amdgcn_mfma_f32_16x16x32_bf16(cv.s, av, acc[ct], 0, 0, 0);
        }
        av = av_next;
    }

    float ss = 0.0f;
#pragma unroll
    for (int ct = 0; ct < NCT; ++ct) {
        f32x4 b4 = *(const f32x4*)(bias + ct * 16 + quad * 4);
#pragma unroll
        for (int r = 0; r < 4; ++r) {
            float v = acc[ct][r] + b4[r];
            if (ACTNORM) { v = fmaxf(v, 0.0f); ss += v * v; }
            acc[ct][r] = v;
        }
    }
    float scale = 1.0f;
    if (ACTNORM) {
        ss += __shfl_xor(ss, 16, 64);
        ss += __shfl_xor(ss, 32, 64);
        scale = 1.0f / fmaxf(sqrtf(ss), 1e-12f);
    }
    if (mynode < n_nodes) {
#pragma unroll
        for (int ct = 0; ct < NCT; ++ct) {
            int c0 = ct * 16 + quad * 4;
            u16x4 o = { f2bf(acc[ct][0] * scale), f2bf(acc[ct][1] * scale),
                        f2bf(acc[ct][2] * scale), f2bf(acc[ct][3] * scale) };
            if (DUAL) {
                if (c0 < 40) *(u16x4*)(Zbuf + (size_t)mynode * 40 + c0) = o;
                else         *(u16x4*)(Ybuf + (size_t)mynode * 40 + (c0 - 40)) = o;
            } else {
                *(u16x4*)(out + (size_t)mynode * out_stride + c0) = o;
            }
        }
    }
}

// ---------------------------------------------------------------------------
// Layer-2 finish: out[n] = mean_{nb}(Y2[nb]) + Z2[n]. One wave per node,
// 8 lanes per 80B Y2 row (stride 40; lanes 5..7 read in-region data that is
// discarded by the sub<5 write guard and never crosses the shfl_xor groups).
__global__ void combine_kernel(const unsigned short* __restrict__ Y2,
                               const unsigned short* __restrict__ Z2,
                               const int* __restrict__ csr,
                               const int* __restrict__ row_start,
                               const int* __restrict__ deg,
                               void* __restrict__ out,
                               const int* __restrict__ gflag) {
    int node = blockIdx.x * 4 + (threadIdx.x >> 6);
    if (node >= N_NODES_C) return;
    int lane = threadIdx.x & 63;
    int g = lane >> 3, sub = lane & 7;
    int start = row_start[node], d = deg[node];
    const int* cp = csr + start;
    float a[8] = {0,0,0,0,0,0,0,0};
    int rd = (sub < 5) ? sub : 4;          // keep OOB-safe within allocated rows
    int nfull = d >> 3, rem = d & 7;
    int i = 0;
    for (; i + 2 <= nfull; i += 2) {
        int nb0 = cp[i * 8 + g];
        int nb1 = cp[i * 8 + 8 + g];
        u32x4 r0 = *(const u32x4*)(Y2 + (size_t)nb0 * 40 + rd * 8);
        u32x4 r1 = *(const u32x4*)(Y2 + (size_t)nb1 * 40 + rd * 8);
        acc8(a, r0); acc8(a, r1);
    }
    if (i < nfull) {
        int nb = cp[i * 8 + g];
        u32x4 r = *(const u32x4*)(Y2 + (size_t)nb * 40 + rd * 8);
        acc8(a, r);
    }
    if (g < rem) {
        int nb = cp[nfull * 8 + g];
        u32x4 r = *(const u32x4*)(Y2 + (size_t)nb * 40 + rd * 8);
        acc8(a, r);
    }
#pragma unroll
    for (int j = 0; j < 8; ++j) {
        a[j] += __shfl_xor(a[j], 8, 64);
        a[j] += __shfl_xor(a[j], 16, 64);
        a[j] += __shfl_xor(a[j], 32, 64);
    }
    if (g == 0 && sub < 5) {
        float inv = (d > 0) ? 1.0f / (float)d : 0.0f;
        u32x4 z = *(const u32x4*)(Z2 + (size_t)node * 40 + sub * 8);
        float v[8];
        v[0] = a[0] * inv + bf_lo(z.x); v[1] = a[1] * inv + bf_hi(z.x);
        v[2] = a[2] * inv + bf_lo(z.y); v[3] = a[3] * inv + bf_hi(z.y);
        v[4] = a[4] * inv + bf_lo(z.z); v[5] = a[5] * inv + bf_hi(z.z);
        v[6] = a[6] * inv + bf_lo(z.w); v[7] = a[7] * inv + bf_hi(z.w);
        if (*gflag) {
            u32x4 o;
            o.x = (unsigned)f2bf(v[0]) | ((unsigned)f2bf(v[1]) << 16);
            o.y = (unsigned)f2bf(v[2]) | ((unsigned)f2bf(v[3]) << 16);
            o.z = (unsigned)f2bf(v[4]) | ((unsigned)f2bf(v[5]) << 16);
            o.w = (unsigned)f2bf(v[6]) | ((unsigned)f2bf(v[7]) << 16);
            *(u32x4*)((unsigned short*)out + (size_t)node * 40 + sub * 8) = o;
        } else {
            float* op = (float*)out + (size_t)node * 40 + sub * 8;
            f32x4 o0 = { v[0], v[1], v[2], v[3] };
            f32x4 o1 = { v[4], v[5], v[6], v[7] };
            *(f32x4*)op = o0;
            *(f32x4*)(op + 4) = o1;
        }
    }
}

// ---------------------------------------------------------------------------
extern "C" void kernel_launch(void* const* d_in, const int* in_sizes, int n_in,
                              void* d_out, int out_size, void* d_ws, size_t ws_size,
                              hipStream_t stream) {
    const void* feats = d_in[0];
    const int*  src   = (const int*)d_in[1];
    const int*  dst   = (const int*)d_in[2];

    char* ws = (char*)d_ws;
    unsigned short* X0   = (unsigned short*)ws;                        // 51,200,000
    unsigned short* X1   = (unsigned short*)(ws + 51200000);           // 51,200,000
    unsigned short* Wt   = (unsigned short*)(ws + 102400000);          //   ~283,000
    float*          bcat = (float*)(ws + 102912000);                   //     1,344
    unsigned short* Y2   = (unsigned short*)(ws + 102916096);          //  8,000,000 (stride 40)
    unsigned short* Z2   = (unsigned short*)(ws + 115716096);          //  8,000,000 (stride 40)
    unsigned*       pairs= (unsigned*)(ws + 102916096);                // alias Y2 (pre-GEMM only), 7.2 MB
    int*  csr       = (int*)(ws + 128516096);                          //  6,400,000
    int*  row_start = (int*)(ws + 134916096);                          //    400,000
    int*  deg       = (int*)(ws + 135316096);                          //    400,000
    int*  boff      = (int*)(ws + 135718144);                          // (N_BUCK+1)*4
    int*  bcur      = (int*)(ws + 135720192);                          // N_BUCK*4
    int*  gflag     = (int*)(ws + 135722240);

    // ---- dtype probe + bucket cursor init (no memsets needed) ----
    detect_init<<<1, 64, 0, stream>>>(feats, gflag, bcur);

    // ---- bucketed CSR build ----
    partition2<<<PART_NB, 256, 0, stream>>>(src, dst, bcur, pairs);
    mkboff_kernel<<<1, 64, 0, stream>>>(bcur, boff);
    bucket_fill<<<N_BUCK, 256, 0, stream>>>(pairs, boff, csr, row_start, deg);

    // ---- weights ----
    prep_weights<<<336, 256, 0, stream>>>(
        d_in[3], d_in[4], d_in[5], d_in[6],
        d_in[7], d_in[8], d_in[9], d_in[10],
        d_in[11], d_in[12], d_in[13], d_in[14], Wt, bcat, gflag);

    const int gblk = (N_NODES_C + 15) / 16;   // 4 nodes/wave, 16 nodes/block
    const int cblk = (N_NODES_C + 3) / 4;
    const int mblk = (N_NODES_C + 63) / 64;

    // layer 0: feats -> X0 = [self | mean] -> X1[:,0:128]
    gather_kernel<<<gblk, 256, 0, stream>>>(feats, 128, 2, 1, csr, row_start, deg, X0, gflag);
    mfma_gemm<8, 8, 32, true, false><<<mblk, 256, 0, stream>>>(
        X0, 256, (const u32x4*)Wt, bcat, X1, 256, nullptr, nullptr, N_NODES_C);

    // layer 1: X1 -> X0[:,0:128]
    gather_kernel<<<gblk, 256, 0, stream>>>(X1, 256, 1, 0, csr, row_start, deg, X1, gflag);
    mfma_gemm<8, 8, 32, true, false><<<mblk, 256, 0, stream>>>(
        X1, 256, (const u32x4*)(Wt + 128 * 256), bcat + 128, X0, 256, nullptr, nullptr, N_NODES_C);

    // layer 2 (transform-then-aggregate): h2 -> Y2 = h2@Wn2, Z2 = h2@Ws2 + b
    mfma_gemm<5, 4, 16, false, true><<<mblk, 256, 0, stream>>>(
        X0, 256, (const u32x4*)(Wt + 65536), bcat + 256, nullptr, 0, Y2, Z2, N_NODES_C);

    // out = mean(Y2[nbrs]) + Z2
    combine_kernel<<<cblk, 256, 0, stream>>>(Y2, Z2, csr, row_start, deg, d_out, gflag);
}